// Round 3
// baseline (207.243 us; speedup 1.0000x reference)
//
#include <hip/hip_runtime.h>

#define HHI 1024
#define WWI 1024
#define NI  16
#define BW  64
#define BH  32
#define GXD (WWI / BW)        // 16
#define GYD (HHI / BH)        // 32
#define NB  (GXD * GYD * NI)  // 8192
#define EPSF  1.1920929e-07f
#define EPS64 7.62939453125e-06f   // 64*EPSF (exact, 2^-17)
#define T1 0.3249196962329063f     // tan(pi/10)
#define T2 1.3763819204711735f     // tan(3pi/10)

__device__ __forceinline__ int clampi(int v, int hi) { return v < 0 ? 0 : (v > hi ? hi : v); }
__device__ __forceinline__ int refli(int v, int n)  { return v < 0 ? -v : (v >= n ? 2 * n - 2 - v : v); }
__device__ __forceinline__ float frcp(float x) { return __builtin_amdgcn_rcpf(x); }

// LDS pool layout (bytes):
//  s_t  [36][68] @ 0      (9792)   both paths
//  fast: h1[36][64] @ 9792, h2 @ 19008, h3 @ 28224   (9216 each)
//  gen : ggx[34][66] @ 9792, ggy @ 18768             (8976 each)
//  s_e  [34][72] @ 37440  (9792)   both paths (col slot = global_col - bx0 + 4)
#define POOL_BYTES 47232

template <bool USE_WS>
__global__ __launch_bounds__(256) void nms_main(
    const float* __restrict__ tru, const float* __restrict__ prd,
    float* __restrict__ partial)
{
    __shared__ __align__(16) char poolc[POOL_BYTES];
    __shared__ float sred[4];
    float (*s_t)[68] = (float(*)[68])(poolc);
    float (*h1)[64]  = (float(*)[64])(poolc + 9792);
    float (*h2)[64]  = (float(*)[64])(poolc + 19008);
    float (*h3)[64]  = (float(*)[64])(poolc + 28224);
    float (*ggx)[66] = (float(*)[66])(poolc + 9792);
    float (*ggy)[66] = (float(*)[66])(poolc + 18768);
    float (*se)[72]  = (float(*)[72])(poolc + 37440);

    const int tid  = threadIdx.x;
    const int lane = tid & 63;
    const int wave = tid >> 6;
    const int bx0 = blockIdx.x * BW;
    const int by0 = blockIdx.y * BH;
    const bool border = (blockIdx.x == 0) | (blockIdx.x == GXD - 1) |
                        (blockIdx.y == 0) | (blockIdx.y == GYD - 1);
    const float* timg = tru + (size_t)blockIdx.z * (HHI * WWI);
    const float* pimg = prd + (size_t)blockIdx.z * (HHI * WWI);

    float term = 0.f;

    if (!border) {
        // ---------------- FAST PATH (no clamping anywhere) ----------------
        // stage t: rows by0-2 .. by0+33, cols bx0-2 .. bx0+65
        for (int r = wave; r < 36; r += 4) {
            const float* rp = timg + (size_t)(by0 - 2 + r) * WWI + (bx0 - 2);
            s_t[r][lane] = rp[lane];
            if (lane < 4) s_t[r][64 + lane] = rp[64 + lane];
        }
        // stage e: rows by0-1 .. by0+32, col slot c <-> global col bx0+c-4 (slots 3..68)
        for (int r = wave; r < 34; r += 4) {
            const float* rp = pimg + (size_t)(by0 - 1 + r) * WWI + (bx0 - 1);
            se[r][3 + lane] = __expf(rp[lane]);
            if (lane < 2) se[r][67 + lane] = __expf(rp[64 + lane]);
        }
        __syncthreads();

        // horizontal 5-tap composites over 36 rows x 16 col-groups
        for (int j = tid; j < 36 * 16; j += 256) {
            const int r = j >> 4, c0 = (j & 15) * 4;
            float4 a = *(const float4*)&s_t[r][c0];
            float4 b = *(const float4*)&s_t[r][c0 + 4];
            const float t0 = a.x, t1 = a.y, t2 = a.z, t3 = a.w;
            const float t4 = b.x, t5 = b.y, t6 = b.z, t7 = b.w;
            float4 o1, o2, o3; float p04, p13;
            p04 = t0 + t4; p13 = t1 + t3;
            o1.x = p04 - 2.f * t2; o2.x = p04 + 4.f * p13 + 6.f * t2;
            o3.x = (t4 - t0) + 2.f * (t3 - t1);
            p04 = t1 + t5; p13 = t2 + t4;
            o1.y = p04 - 2.f * t3; o2.y = p04 + 4.f * p13 + 6.f * t3;
            o3.y = (t5 - t1) + 2.f * (t4 - t2);
            p04 = t2 + t6; p13 = t3 + t5;
            o1.z = p04 - 2.f * t4; o2.z = p04 + 4.f * p13 + 6.f * t4;
            o3.z = (t6 - t2) + 2.f * (t5 - t3);
            p04 = t3 + t7; p13 = t4 + t6;
            o1.w = p04 - 2.f * t5; o2.w = p04 + 4.f * p13 + 6.f * t5;
            o3.w = (t7 - t3) + 2.f * (t6 - t4);
            *(float4*)&h1[r][c0] = o1;
            *(float4*)&h2[r][c0] = o2;
            *(float4*)&h3[r][c0] = o3;
        }
        __syncthreads();

        // vertical pass + classification: thread = 4 cols x 2 rows
        const int cg = tid & 15, rg = tid >> 4;
        const int r0 = rg * 2, c0 = cg * 4;
        float4 A[6], B[6], C[6];
        #pragma unroll
        for (int i = 0; i < 6; ++i) {
            A[i] = *(const float4*)&h1[r0 + i][c0];
            B[i] = *(const float4*)&h2[r0 + i][c0];
            C[i] = *(const float4*)&h3[r0 + i][c0];
        }
        #pragma unroll
        for (int rr = 0; rr < 2; ++rr) {
            const float* a0 = (const float*)(A + rr);
            const float* a1 = (const float*)(A + rr + 1);
            const float* a2 = (const float*)(A + rr + 2);
            const float* a3 = (const float*)(A + rr + 3);
            const float* a4 = (const float*)(A + rr + 4);
            const float* b0 = (const float*)(B + rr);
            const float* b2 = (const float*)(B + rr + 2);
            const float* b4 = (const float*)(B + rr + 4);
            const float* c0p = (const float*)(C + rr);
            const float* c1p = (const float*)(C + rr + 1);
            const float* c3p = (const float*)(C + rr + 3);
            const float* c4p = (const float*)(C + rr + 4);
            const int er = r0 + rr + 1;
            float4 ecq = *(const float4*)&se[er][c0 + 4];
            const float* ecf = (const float*)&ecq;
            #pragma unroll
            for (int k = 0; k < 4; ++k) {
                float gxx = (a0[k] + a4[k]) + 4.f * (a1[k] + a3[k]) + 6.f * a2[k];
                float gxy = (c4p[k] - c0p[k]) + 2.f * (c3p[k] - c1p[k]);
                float gyy = (b0[k] + b4[k]) - 2.f * b2[k];
                float sarg = EPS64 - gxy;
                float num = (sarg > 0.f) ? gyy : ((sarg < 0.f) ? -gyy : 0.f);
                float v = num * frcp(gxx + EPS64);
                bool c2v = (v > T2);
                bool c1v = (v > T1) & !c2v;
                bool c0v = (v >= -T1) & (v <= T1);
                bool c3v = (v < -T2);
                bool have = c2v | c1v | c0v | c3v;   // NaN -> all false
                const int ecc = c0 + 4 + k;
                int r1 = c0v ? er : er - 1;
                int r2 = c0v ? er : er + 1;
                int col1 = c2v ? ecc : (c1v ? ecc + 1 : ecc - 1);
                int col2 = c2v ? ecc : (c1v ? ecc - 1 : ecc + 1);
                float ec = ecf[k];
                float dsum = se[r1][col1] + ec + se[r2][col2];
                float val = ec * frcp(dsum + EPSF);
                term += have ? val : 0.f;
            }
        }
    } else {
        // ---------------- GENERAL PATH (nested clamp / reflect) ----------------
        for (int r = 0; r < 36; ++r) {
            if ((r & 3) != wave) continue;
            const int gy = clampi(by0 - 2 + r, HHI - 1);
            const float* rp = timg + (size_t)gy * WWI;
            s_t[r][lane] = rp[clampi(bx0 - 2 + lane, WWI - 1)];
            if (lane < 4) s_t[r][64 + lane] = rp[clampi(bx0 + 62 + lane, WWI - 1)];
        }
        for (int r = 0; r < 34; ++r) {
            if ((r & 3) != wave) continue;
            const int gy = refli(by0 - 1 + r, HHI);
            const float* rp = pimg + (size_t)gy * WWI;
            se[r][3 + lane] = __expf(rp[refli(bx0 - 1 + lane, WWI)]);
            if (lane < 2) se[r][67 + lane] = __expf(rp[refli(bx0 + 63 + lane, WWI)]);
        }
        __syncthreads();

        // first sobel at halo1 slots [34][66] with nested clamp
        for (int r = wave; r < 34; r += 4) {
            for (int cc = lane; cc < 66; cc += 64) {
                const int g1y = clampi(by0 - 1 + r, HHI - 1);
                const int g1x = clampi(bx0 - 1 + cc, WWI - 1);
                const int ym = clampi(g1y - 1, HHI - 1) - by0 + 2;
                const int y0 = g1y - by0 + 2;
                const int yp = clampi(g1y + 1, HHI - 1) - by0 + 2;
                const int xm = clampi(g1x - 1, WWI - 1) - bx0 + 2;
                const int x0 = g1x - bx0 + 2;
                const int xp = clampi(g1x + 1, WWI - 1) - bx0 + 2;
                float tmm = s_t[ym][xm], tm0 = s_t[ym][x0], tmp_ = s_t[ym][xp];
                float t0m = s_t[y0][xm],                    t0p = s_t[y0][xp];
                float tpm = s_t[yp][xm], tp0 = s_t[yp][x0], tpp = s_t[yp][xp];
                ggx[r][cc] = ((tmp_ - tmm) + 2.f * (t0p - t0m) + (tpp - tpm)) * 0.125f;
                ggy[r][cc] = ((tpm - tmm) + 2.f * (tp0 - tm0) + (tpp - tmp_)) * 0.125f;
            }
        }
        __syncthreads();

        for (int k = 0; k < 8; ++k) {
            const int oy = wave + 4 * k;   // 0..31
            const int ox = lane;
            const int y = by0 + oy, x = bx0 + ox;
            const int rm = clampi(y - 1, HHI - 1) - by0 + 1;
            const int rc = oy + 1;
            const int rp_ = clampi(y + 1, HHI - 1) - by0 + 1;
            const int cm = clampi(x - 1, WWI - 1) - bx0 + 1;
            const int cc0 = ox + 1;
            const int cp = clampi(x + 1, WWI - 1) - bx0 + 1;

            float gxx = ((ggx[rm][cp] - ggx[rm][cm]) + 2.f * (ggx[rc][cp] - ggx[rc][cm])
                       + (ggx[rp_][cp] - ggx[rp_][cm])) * 0.125f;
            float gxy = ((ggy[rm][cp] - ggy[rm][cm]) + 2.f * (ggy[rc][cp] - ggy[rc][cm])
                       + (ggy[rp_][cp] - ggy[rp_][cm])) * 0.125f;
            float gyy = ((ggy[rp_][cm] - ggy[rm][cm]) + 2.f * (ggy[rp_][cc0] - ggy[rm][cc0])
                       + (ggy[rp_][cp] - ggy[rm][cp])) * 0.125f;

            float sarg = EPSF - gxy;
            float num = (sarg > 0.f) ? gyy : ((sarg < 0.f) ? -gyy : 0.f);
            float v = num * frcp(gxx + EPSF);
            bool c2v = (v > T2);
            bool c1v = (v > T1) & !c2v;
            bool c0v = (v >= -T1) & (v <= T1);
            bool c3v = (v < -T2);
            bool have = c2v | c1v | c0v | c3v;

            const int er = oy + 1, ecc = ox + 4;
            const int erm = refli(y - 1, HHI) - by0 + 1;
            const int erp = refli(y + 1, HHI) - by0 + 1;
            const int ecm = refli(x - 1, WWI) - bx0 + 4;
            const int ecp = refli(x + 1, WWI) - bx0 + 4;
            int r1 = c0v ? er : erm;
            int r2 = c0v ? er : erp;
            int col1 = c2v ? ecc : (c1v ? ecp : ecm);
            int col2 = c2v ? ecc : (c1v ? ecm : ecp);
            float ec = se[er][ecc];
            float dsum = se[r1][col1] + ec + se[r2][col2];
            float val = ec * frcp(dsum + EPSF);
            term += have ? val : 0.f;
        }
    }

    // block reduction
    for (int off = 32; off; off >>= 1) term += __shfl_down(term, off, 64);
    if (lane == 0) sred[wave] = term;
    __syncthreads();
    if (tid == 0) {
        float b = sred[0] + sred[1] + sred[2] + sred[3];
        if (USE_WS) {
            partial[((size_t)blockIdx.z * GYD + blockIdx.y) * GXD + blockIdx.x] = b;
        } else {
            atomicAdd(partial, b);
        }
    }
}

__global__ __launch_bounds__(1024) void reduce_kernel(
    const float* __restrict__ partial, float* __restrict__ out)
{
    __shared__ float s_red[16];
    float s = 0.f;
    for (int i = threadIdx.x; i < NB; i += 1024) s += partial[i];
    for (int off = 32; off; off >>= 1) s += __shfl_down(s, off, 64);
    if ((threadIdx.x & 63) == 0) s_red[threadIdx.x >> 6] = s;
    __syncthreads();
    if (threadIdx.x == 0) {
        float b = 0.f;
        #pragma unroll
        for (int i = 0; i < 16; ++i) b += s_red[i];
        out[0] = b;
    }
}

extern "C" void kernel_launch(void* const* d_in, const int* in_sizes, int n_in,
                              void* d_out, int out_size, void* d_ws, size_t ws_size,
                              hipStream_t stream) {
    const float* tru = (const float*)d_in[0];
    const float* prd = (const float*)d_in[1];
    float* out = (float*)d_out;
    dim3 grid(GXD, GYD, NI);
    dim3 block(256, 1, 1);
    if (ws_size >= (size_t)NB * sizeof(float)) {
        float* ws = (float*)d_ws;
        hipLaunchKernelGGL(nms_main<true>, grid, block, 0, stream, tru, prd, ws);
        hipLaunchKernelGGL(reduce_kernel, dim3(1), dim3(1024), 0, stream, ws, out);
    } else {
        hipMemsetAsync(out, 0, sizeof(float), stream);
        hipLaunchKernelGGL(nms_main<false>, grid, block, 0, stream, tru, prd, out);
    }
}

// Round 4
// 69.441 us; speedup vs baseline: 2.9844x; 2.9844x over previous
//
#include <hip/hip_runtime.h>

#define HHI 1024
#define WWI 1024
#define NI  16
#define EPSF  1.1920929e-07f
#define EPS64 7.62939453125e-06f   // 64*EPSF (exact)
#define T1 0.3249196962329063f     // tan(pi/10)
#define T2 1.3763819204711735f     // tan(3pi/10)

#define GX  16                     // interior x-strips (64 cols each)
#define GYB 8                      // y-blocks (128 rows = 4 waves x 32 rows)
#define FRB 4                      // frame-block slots in grid.x (16..19)
#define NB_INT (GX * GYB * NI)     // 2048
#define NB_FRM (FRB * GYB * NI)    // 512
#define NB_TOT (NB_INT + NB_FRM)   // 2560
#define NFRAME 8176                // 2*1024 + 2*1024 + 4*1020 frame pixels/img

__device__ __forceinline__ int clampi(int v, int hi) { return v < 0 ? 0 : (v > hi ? hi : v); }
__device__ __forceinline__ int refli(int v, int n)  { return v < 0 ? -v : (v >= n ? 2*n-2-v : v); }
__device__ __forceinline__ float frcp(float x) { return __builtin_amdgcn_rcpf(x); }

template <bool USE_WS>
__global__ __launch_bounds__(256, 6) void nms_main(
    const float* __restrict__ tru, const float* __restrict__ prd,
    float* __restrict__ partial)
{
    __shared__ float sred[4];
    const int tid  = threadIdx.x;
    const int lane = tid & 63;
    const int wave = tid >> 6;
    const int z = blockIdx.z;
    const float* timg = tru + (size_t)z * (HHI * WWI);
    const float* pimg = prd + (size_t)z * (HHI * WWI);
    float term = 0.f;

    if (blockIdx.x < GX) {
        // -------- interior: per-wave 64x32 strip, register-ring streaming --------
        const int x  = blockIdx.x * 64 + lane;
        const int Y0 = blockIdx.y * 128 + wave * 32;
        const int ci0 = clampi(x - 2, WWI - 1);
        const int ci1 = clampi(x - 1, WWI - 1);
        const int ci2 = x;
        const int ci3 = clampi(x + 1, WWI - 1);
        const int ci4 = clampi(x + 2, WWI - 1);
        const bool mx = (x >= 2) & (x <= WWI - 3);
        float H1[5], H2[5], H3[5];
        #pragma unroll 1
        for (int ch = 0; ch < 8; ++ch) {
            #pragma unroll
            for (int pos = 0; pos < 5; ++pos) {
                const int i = ch * 5 + pos;      // stage index 0..39 (36..39 skipped)
                if (i < 36) {
                    const int s  = Y0 - 2 + i;
                    const int gy = clampi(s, HHI - 1);
                    const float* trow = timg + (size_t)gy * WWI;
                    float t0 = trow[ci0], t1 = trow[ci1], t2 = trow[ci2],
                          t3 = trow[ci3], t4 = trow[ci4];
                    float s04 = t0 + t4, s13 = t1 + t3;
                    // composed horizontal 5-taps (x64 unnormalized):
                    H1[pos] = s04 - 2.f * t2;                    // [1,0,-2,0,1]  (gxx)
                    H2[pos] = s04 + 4.f * s13 + 6.f * t2;        // [1,4,6,4,1]   (gyy)
                    H3[pos] = (t4 - t0) + 2.f * (t3 - t1);       // [-1,-2,0,2,1] (gxy)
                    if (i >= 4) {
                        const int y = s - 2;
                        if (y >= 2 && y <= HHI - 3) {
                            const int q0 = (pos + 1) % 5, q1 = (pos + 2) % 5,
                                      q2 = (pos + 3) % 5, q3 = (pos + 4) % 5, q4 = pos;
                            float gxx = (H1[q0] + H1[q4]) + 4.f * (H1[q1] + H1[q3]) + 6.f * H1[q2];
                            float gyy = (H2[q0] + H2[q4]) - 2.f * H2[q2];
                            float gxy = (H3[q4] - H3[q0]) + 2.f * (H3[q3] - H3[q1]);
                            float sarg = EPS64 - gxy;
                            float num = (sarg > 0.f) ? gyy : ((sarg < 0.f) ? -gyy : 0.f);
                            float v = num * frcp(gxx + EPS64);
                            bool c2v = (v > T2);
                            bool c1v = (v > T1) & !c2v;
                            bool c0v = (v >= -T1) & (v <= T1);
                            bool c3v = (v < -T2);
                            bool have = c2v | c1v | c0v | c3v;   // NaN -> none
                            int dr  = c0v ? 0 : 1;
                            int co1 = c2v ? ci2 : (c1v ? ci3 : ci1);
                            int co2 = c2v ? ci2 : (c1v ? ci1 : ci3);
                            float ec = __expf(pimg[(size_t)y * WWI + ci2]);
                            float d1 = __expf(pimg[(size_t)(y - dr) * WWI + co1]);
                            float d2 = __expf(pimg[(size_t)(y + dr) * WWI + co2]);
                            float val = ec * frcp(d1 + ec + d2 + EPSF);
                            term += (have & mx) ? val : 0.f;
                        }
                    }
                }
            }
        }
    } else {
        // -------- frame: exact nested replicate-pad cascade, 2-px border --------
        const int fid = (blockIdx.x - GX) * GYB + blockIdx.y;   // 0..31
        const int p = fid * 256 + tid;
        const bool valid = p < NFRAME;
        int y, x;
        if (p < 2048)      { y = p >> 10;                x = p & 1023; }
        else if (p < 4096) { y = 1022 + ((p - 2048) >> 10); x = p & 1023; }
        else { int q = p - 4096; y = 2 + (q >> 2); int xi = q & 3; x = (xi < 2) ? xi : 1020 + xi; }
        if (!valid) { y = 2; x = 0; }

        int R1[3], C1[3], R2[3][3], C2[3][3];
        #pragma unroll
        for (int a = 0; a < 3; ++a) { R1[a] = clampi(y + a - 1, HHI - 1); C1[a] = clampi(x + a - 1, WWI - 1); }
        #pragma unroll
        for (int a = 0; a < 3; ++a)
            #pragma unroll
            for (int e = 0; e < 3; ++e) {
                R2[a][e] = clampi(R1[a] + e - 1, HHI - 1);
                C2[a][e] = clampi(C1[a] + e - 1, WWI - 1);
            }
        // sobel_x = vx (x) hx, sobel_y = vy (x) hy   (unnormalized; /8 per stage deferred)
        const int hx[3] = {-1, 0, 1}, vx[3] = {1, 2, 1};
        const int hy[3] = {1, 2, 1},  vy[3] = {-1, 0, 1};
        float gxu[3][3], gyu[3][3];
        #pragma unroll
        for (int a = 0; a < 3; ++a)
            #pragma unroll
            for (int b = 0; b < 3; ++b) {
                float sx = 0.f, sy = 0.f;
                #pragma unroll
                for (int e = 0; e < 3; ++e)
                    #pragma unroll
                    for (int f = 0; f < 3; ++f) {
                        const int wx = hx[f] * vx[e], wy = hy[f] * vy[e];
                        if (wx | wy) {
                            float tv = timg[(size_t)R2[a][e] * WWI + C2[b][f]];
                            if (wx) sx += (float)wx * tv;
                            if (wy) sy += (float)wy * tv;
                        }
                    }
                gxu[a][b] = sx; gyu[a][b] = sy;
            }
        float gxx = 0.f, gxy = 0.f, gyy = 0.f;
        #pragma unroll
        for (int a = 0; a < 3; ++a)
            #pragma unroll
            for (int b = 0; b < 3; ++b) {
                const int w1 = hx[b] * vx[a], w2 = hy[b] * vy[a];
                if (w1) { gxx += (float)w1 * gxu[a][b]; gxy += (float)w1 * gyu[a][b]; }
                if (w2) { gyy += (float)w2 * gyu[a][b]; }
            }
        float sarg = EPS64 - gxy;                    // all x64 unnormalized
        float num = (sarg > 0.f) ? gyy : ((sarg < 0.f) ? -gyy : 0.f);
        float v = num * frcp(gxx + EPS64);
        bool c2v = (v > T2);
        bool c1v = (v > T1) & !c2v;
        bool c0v = (v >= -T1) & (v <= T1);
        bool c3v = (v < -T2);
        bool have = c2v | c1v | c0v | c3v;
        int r1 = c0v ? y : refli(y - 1, HHI);
        int r2 = c0v ? y : refli(y + 1, HHI);
        int xm = refli(x - 1, WWI), xp = refli(x + 1, WWI);
        int co1 = c2v ? x : (c1v ? xp : xm);
        int co2 = c2v ? x : (c1v ? xm : xp);
        float ec = __expf(pimg[(size_t)y * WWI + x]);
        float d1 = __expf(pimg[(size_t)r1 * WWI + co1]);
        float d2 = __expf(pimg[(size_t)r2 * WWI + co2]);
        float val = ec * frcp(d1 + ec + d2 + EPSF);
        term += (have & valid) ? val : 0.f;
    }

    // block reduction: wave shuffle + cross-wave LDS
    for (int off = 32; off; off >>= 1) term += __shfl_down(term, off, 64);
    if (lane == 0) sred[wave] = term;
    __syncthreads();
    if (tid == 0) {
        float b = sred[0] + sred[1] + sred[2] + sred[3];
        if (USE_WS) {
            const int slot = (blockIdx.x < GX)
                ? ((z * GYB + blockIdx.y) * GX + blockIdx.x)
                : (NB_INT + z * 32 + ((blockIdx.x - GX) * GYB + blockIdx.y));
            partial[slot] = b;
        } else {
            atomicAdd(partial, b);
        }
    }
}

__global__ __launch_bounds__(1024) void reduce_kernel(
    const float* __restrict__ partial, float* __restrict__ out)
{
    __shared__ float s_red[16];
    float s = 0.f;
    for (int i = threadIdx.x; i < NB_TOT; i += 1024) s += partial[i];
    for (int off = 32; off; off >>= 1) s += __shfl_down(s, off, 64);
    if ((threadIdx.x & 63) == 0) s_red[threadIdx.x >> 6] = s;
    __syncthreads();
    if (threadIdx.x == 0) {
        float b = 0.f;
        #pragma unroll
        for (int i = 0; i < 16; ++i) b += s_red[i];
        out[0] = b;
    }
}

extern "C" void kernel_launch(void* const* d_in, const int* in_sizes, int n_in,
                              void* d_out, int out_size, void* d_ws, size_t ws_size,
                              hipStream_t stream) {
    const float* tru = (const float*)d_in[0];
    const float* prd = (const float*)d_in[1];
    float* out = (float*)d_out;
    dim3 grid(GX + FRB, GYB, NI);
    dim3 block(256, 1, 1);
    if (ws_size >= (size_t)NB_TOT * sizeof(float)) {
        float* ws = (float*)d_ws;
        hipLaunchKernelGGL(nms_main<true>, grid, block, 0, stream, tru, prd, ws);
        hipLaunchKernelGGL(reduce_kernel, dim3(1), dim3(1024), 0, stream, ws, out);
    } else {
        hipMemsetAsync(out, 0, sizeof(float), stream);
        hipLaunchKernelGGL(nms_main<false>, grid, block, 0, stream, tru, prd, out);
    }
}